// Round 1
// baseline (1650.164 us; speedup 1.0000x reference)
//
#include <hip/hip_runtime.h>
#include <math.h>

// Problem constants
#define Bc 2
#define Tc 2048
#define Dc 1024
#define Hc 16
#define HDc 64
#define BT (Bc*Tc)              // 4096
#define SCALE 0.35355339059327379f   // 64^-0.25

#define TILE 64
#define TK 16
#define LDP (TILE + 4)          // LDS pad

// ---------------------------------------------------------------------------
// proj: C(M=BT x N=Dc) = A(BT x Dc) * W(Dc x Dc)^T + bias, with epilogue MODE
// MODE 0: plain, write (B,T,D) row-major (output projection)
// MODE 1: RoPE + SCALE, write (B,H,T,HD)   (q and k)
// MODE 2: plain, write (B,H,T,HD)          (v)
// ---------------------------------------------------------------------------
template<int MODE>
__global__ __launch_bounds__(256)
void proj_kernel(const float* __restrict__ A, const float* __restrict__ W,
                 const float* __restrict__ bias, float* __restrict__ out,
                 const float* __restrict__ cosp, const float* __restrict__ sinp)
{
    const int K = Dc;
    __shared__ float As[TK][LDP];   // As[k][row]
    __shared__ float Bs[TK][LDP];   // Bs[k][col]
    const int tid = threadIdx.x;
    const int tx = tid & 15, ty = tid >> 4;
    const int n0 = blockIdx.x * TILE;
    const int m0 = blockIdx.y * TILE;
    const int lc = tid & 15;        // k offset 0..15
    const int lr = tid >> 4;        // row/col base 0..15

    float acc[4][4] = {};

    for (int k0 = 0; k0 < K; k0 += TK) {
        #pragma unroll
        for (int i = 0; i < 4; i++) {
            int r = lr + 16*i;
            As[lc][r] = A[(size_t)(m0 + r)*K + k0 + lc];
            Bs[lc][r] = W[(size_t)(n0 + r)*K + k0 + lc];
        }
        __syncthreads();
        #pragma unroll
        for (int kk = 0; kk < TK; kk++) {
            float4 av = *(const float4*)&As[kk][ty*4];
            float4 bv = *(const float4*)&Bs[kk][tx*4];
            float a_[4] = {av.x, av.y, av.z, av.w};
            float b_[4] = {bv.x, bv.y, bv.z, bv.w};
            #pragma unroll
            for (int i = 0; i < 4; i++)
                #pragma unroll
                for (int j = 0; j < 4; j++)
                    acc[i][j] += a_[i] * b_[j];
        }
        __syncthreads();
    }

    #pragma unroll
    for (int i = 0; i < 4; i++) {
        const int gm = m0 + ty*4 + i;       // row in [0, BT)
        const int b  = gm / Tc;
        const int t  = gm % Tc;
        if (MODE == 0) {
            #pragma unroll
            for (int j = 0; j < 4; j++) {
                int gn = n0 + tx*4 + j;
                out[(size_t)gm*Dc + gn] = acc[i][j] + (bias ? bias[gn] : 0.f);
            }
        } else if (MODE == 1) {
            #pragma unroll
            for (int j = 0; j < 4; j += 2) {
                int gn = n0 + tx*4 + j;     // even
                int h = gn >> 6;
                int d = gn & 63;
                int p = d >> 1;
                float c = cosp[t*(HDc/2) + p];
                float s = sinp[t*(HDc/2) + p];
                float v0 = acc[i][j]   + (bias ? bias[gn]   : 0.f);
                float v1 = acc[i][j+1] + (bias ? bias[gn+1] : 0.f);
                float* o = out + (((size_t)(b*Hc + h)*Tc + t)*HDc + d);
                o[0] = (v0*c - v1*s) * SCALE;
                o[1] = (v0*s + v1*c) * SCALE;
            }
        } else {
            #pragma unroll
            for (int j = 0; j < 4; j++) {
                int gn = n0 + tx*4 + j;
                int h = gn >> 6;
                int d = gn & 63;
                out[((size_t)(b*Hc + h)*Tc + t)*HDc + d] =
                    acc[i][j] + (bias ? bias[gn] : 0.f);
            }
        }
    }
}

// ---------------------------------------------------------------------------
// qk: per (b,h): C(T x T) = q(T x HD) * k(T x HD)^T + mask
// ---------------------------------------------------------------------------
__global__ __launch_bounds__(256)
void qk_kernel(const float* __restrict__ q, const float* __restrict__ k,
               const float* __restrict__ mask, float* __restrict__ qk)
{
    const int z = blockIdx.z;          // b*H + h
    const float* A  = q + (size_t)z * Tc * HDc;
    const float* Bm = k + (size_t)z * Tc * HDc;
    float* C = qk + (size_t)z * Tc * Tc;

    __shared__ float As[TK][LDP];
    __shared__ float Bs[TK][LDP];
    const int tid = threadIdx.x;
    const int tx = tid & 15, ty = tid >> 4;
    const int s0 = blockIdx.x * TILE;
    const int t0 = blockIdx.y * TILE;
    const int lc = tid & 15;
    const int lr = tid >> 4;

    float acc[4][4] = {};

    #pragma unroll
    for (int k0 = 0; k0 < HDc; k0 += TK) {
        #pragma unroll
        for (int i = 0; i < 4; i++) {
            int r = lr + 16*i;
            As[lc][r] = A [(size_t)(t0 + r)*HDc + k0 + lc];
            Bs[lc][r] = Bm[(size_t)(s0 + r)*HDc + k0 + lc];
        }
        __syncthreads();
        #pragma unroll
        for (int kk = 0; kk < TK; kk++) {
            float4 av = *(const float4*)&As[kk][ty*4];
            float4 bv = *(const float4*)&Bs[kk][tx*4];
            float a_[4] = {av.x, av.y, av.z, av.w};
            float b_[4] = {bv.x, bv.y, bv.z, bv.w};
            #pragma unroll
            for (int i = 0; i < 4; i++)
                #pragma unroll
                for (int j = 0; j < 4; j++)
                    acc[i][j] += a_[i] * b_[j];
        }
        __syncthreads();
    }

    #pragma unroll
    for (int i = 0; i < 4; i++) {
        int t = t0 + ty*4 + i;
        #pragma unroll
        for (int j = 0; j < 4; j++) {
            int s = s0 + tx*4 + j;
            C[(size_t)t*Tc + s] = acc[i][j] + mask[(size_t)t*Tc + s];
        }
    }
}

// ---------------------------------------------------------------------------
// softmax stats: one wave per row of qk; rowmax + 1/rowsum
// ---------------------------------------------------------------------------
__global__ __launch_bounds__(256)
void softmax_stats_kernel(const float* __restrict__ qk,
                          float* __restrict__ rowmax, float* __restrict__ rowinv)
{
    const int wave = threadIdx.x >> 6;
    const int lane = threadIdx.x & 63;
    const size_t row = (size_t)blockIdx.x * 4 + wave;   // < B*H*T
    const float4* p = (const float4*)(qk + row * Tc);

    float4 vals[8];
    float m = -INFINITY;
    #pragma unroll
    for (int w = 0; w < 8; w++) {
        vals[w] = p[lane + 64*w];
        m = fmaxf(m, fmaxf(fmaxf(vals[w].x, vals[w].y), fmaxf(vals[w].z, vals[w].w)));
    }
    #pragma unroll
    for (int off = 32; off > 0; off >>= 1)
        m = fmaxf(m, __shfl_xor(m, off, 64));

    float sum = 0.f;
    #pragma unroll
    for (int w = 0; w < 8; w++) {
        sum += __expf(vals[w].x - m) + __expf(vals[w].y - m)
             + __expf(vals[w].z - m) + __expf(vals[w].w - m);
    }
    #pragma unroll
    for (int off = 32; off > 0; off >>= 1)
        sum += __shfl_xor(sum, off, 64);

    if (lane == 0) {
        rowmax[row] = m;
        rowinv[row] = 1.0f / sum;
    }
}

// ---------------------------------------------------------------------------
// wv: per (b,h): out_t(T x HD) = softmax(P) * v ; P read back from qk output,
// exp applied on load, 1/l folded into epilogue. Writes (B,T,D) layout.
// ---------------------------------------------------------------------------
__global__ __launch_bounds__(256)
void wv_kernel(const float* __restrict__ qk, const float* __restrict__ v,
               const float* __restrict__ rowmax, const float* __restrict__ rowinv,
               float* __restrict__ wv)
{
    const int z  = blockIdx.y;           // b*H + h
    const int t0 = blockIdx.x * TILE;
    const float* P = qk + (size_t)z * Tc * Tc;
    const float* V = v  + (size_t)z * Tc * HDc;

    __shared__ float As[TK][LDP];        // As[s][t] = exp(P - m)
    __shared__ float Bs[TK][HDc + 4];    // Bs[s][d]
    const int tid = threadIdx.x;
    const int tx = tid & 15, ty = tid >> 4;
    const int lc = tid & 15;
    const int lr = tid >> 4;

    // preload row maxes for the 4 A-rows this thread stages
    float rm[4];
    #pragma unroll
    for (int i = 0; i < 4; i++)
        rm[i] = rowmax[(size_t)z*Tc + t0 + lr + 16*i];

    float acc[4][4] = {};

    for (int s0 = 0; s0 < Tc; s0 += TK) {
        #pragma unroll
        for (int i = 0; i < 4; i++) {
            int r = lr + 16*i;
            float x = P[(size_t)(t0 + r)*Tc + s0 + lc];
            As[lc][r] = __expf(x - rm[i]);
        }
        {
            int d  = tid & 63;
            int r2 = tid >> 6;           // 0..3
            #pragma unroll
            for (int i = 0; i < 4; i++) {
                int s = r2 + 4*i;
                Bs[s][d] = V[(size_t)(s0 + s)*HDc + d];
            }
        }
        __syncthreads();
        #pragma unroll
        for (int kk = 0; kk < TK; kk++) {
            float4 av = *(const float4*)&As[kk][ty*4];
            float4 bv = *(const float4*)&Bs[kk][tx*4];
            float a_[4] = {av.x, av.y, av.z, av.w};
            float b_[4] = {bv.x, bv.y, bv.z, bv.w};
            #pragma unroll
            for (int i = 0; i < 4; i++)
                #pragma unroll
                for (int j = 0; j < 4; j++)
                    acc[i][j] += a_[i] * b_[j];
        }
        __syncthreads();
    }

    const int b = z / Hc, h = z % Hc;
    #pragma unroll
    for (int i = 0; i < 4; i++) {
        int t = t0 + ty*4 + i;
        float inv = rowinv[(size_t)z*Tc + t];
        #pragma unroll
        for (int j = 0; j < 4; j++) {
            int d = tx*4 + j;
            wv[((size_t)(b*Tc + t))*Dc + h*HDc + d] = acc[i][j] * inv;
        }
    }
}

// ---------------------------------------------------------------------------
extern "C" void kernel_launch(void* const* d_in, const int* in_sizes, int n_in,
                              void* d_out, int out_size, void* d_ws, size_t ws_size,
                              hipStream_t stream)
{
    const float* x    = (const float*)d_in[0];
    const float* mask = (const float*)d_in[1];
    const float* cosp = (const float*)d_in[2];
    const float* sinp = (const float*)d_in[3];
    const float* Wq   = (const float*)d_in[4];
    const float* bq   = (const float*)d_in[5];
    const float* Wk   = (const float*)d_in[6];
    const float* Wv   = (const float*)d_in[7];
    const float* bv   = (const float*)d_in[8];
    const float* Wo   = (const float*)d_in[9];
    const float* bo   = (const float*)d_in[10];

    float* out = (float*)d_out;
    float* qk  = out + (size_t)Bc*Tc*Dc;        // output 1 region

    float* ws = (float*)d_ws;
    const size_t qkv_sz = (size_t)Bc*Hc*Tc*HDc;  // 4,194,304
    float* q_  = ws;
    float* k_  = q_ + qkv_sz;
    float* v_  = k_ + qkv_sz;
    float* rowmax = v_ + qkv_sz;
    float* rowinv = rowmax + (size_t)Bc*Hc*Tc;
    float* wv     = rowinv + (size_t)Bc*Hc*Tc;

    dim3 blk(256);

    // 1) q, k, v projections (+RoPE+scale for q,k)
    dim3 gproj(Dc/TILE, BT/TILE);
    proj_kernel<1><<<gproj, blk, 0, stream>>>(x, Wq, bq,      q_, cosp, sinp);
    proj_kernel<1><<<gproj, blk, 0, stream>>>(x, Wk, nullptr, k_, cosp, sinp);
    proj_kernel<2><<<gproj, blk, 0, stream>>>(x, Wv, bv,      v_, cosp, sinp);

    // 2) qk = q k^T + mask  (writes output 1)
    dim3 gqk(Tc/TILE, Tc/TILE, Bc*Hc);
    qk_kernel<<<gqk, blk, 0, stream>>>(q_, k_, mask, qk);

    // 3) per-row softmax stats
    softmax_stats_kernel<<<dim3(Bc*Hc*Tc/4), blk, 0, stream>>>(qk, rowmax, rowinv);

    // 4) wv = softmax(qk) * v   -> (B,T,D)
    dim3 gwv(Tc/TILE, Bc*Hc);
    wv_kernel<<<gwv, blk, 0, stream>>>(qk, v_, rowmax, rowinv, wv);

    // 5) out = wv Wo^T + bo  (writes output 0)
    proj_kernel<0><<<gproj, blk, 0, stream>>>(wv, Wo, bo, out, nullptr, nullptr);
}

// Round 3
// 859.488 us; speedup vs baseline: 1.9199x; 1.9199x over previous
//
#include <hip/hip_runtime.h>
#include <math.h>

#define Tc 2048
#define Dc 1024
#define Hc 16
#define HDc 64
#define BT 4096                     // B*T
#define SCALE 0.35355339059327379f  // 64^-0.25

typedef _Float16 f16;
typedef __attribute__((ext_vector_type(4))) _Float16 f16x4;
typedef __attribute__((ext_vector_type(8))) _Float16 f16x8;
typedef __attribute__((ext_vector_type(4))) float f32x4;

// ---------------------------------------------------------------------------
// casts
// ---------------------------------------------------------------------------
__global__ __launch_bounds__(256)
void cast1_kernel(const float* __restrict__ in, f16* __restrict__ out, int n4)
{
    int i = blockIdx.x * 256 + threadIdx.x;
    if (i < n4) {
        float4 v = ((const float4*)in)[i];
        f16x4 o = {(f16)v.x, (f16)v.y, (f16)v.z, (f16)v.w};
        ((f16x4*)out)[i] = o;
    }
}

__global__ __launch_bounds__(256)
void cast4_kernel(const float* __restrict__ s0, const float* __restrict__ s1,
                  const float* __restrict__ s2, const float* __restrict__ s3,
                  f16* __restrict__ d0, f16* __restrict__ d1,
                  f16* __restrict__ d2, f16* __restrict__ d3, int n4)
{
    const float* s; f16* d;
    switch (blockIdx.y) {
        case 0:  s = s0; d = d0; break;
        case 1:  s = s1; d = d1; break;
        case 2:  s = s2; d = d2; break;
        default: s = s3; d = d3; break;
    }
    int i = blockIdx.x * 256 + threadIdx.x;
    if (i < n4) {
        float4 v = ((const float4*)s)[i];
        f16x4 o = {(f16)v.x, (f16)v.y, (f16)v.z, (f16)v.w};
        ((f16x4*)d)[i] = o;
    }
}

// ---------------------------------------------------------------------------
// fused QKV projection: C(BT x Dc) = xh * W^T (+bias), epilogue RoPE/scale,
// store f16 (B,H,T,HD).  blockIdx.z: 0=q, 1=k, 2=v
// Block tile 128(M) x 64(N), K-step 32. 4 waves, each 32 rows x 64 cols.
// ---------------------------------------------------------------------------
__global__ __launch_bounds__(256)
void qkv_proj_kernel(const f16* __restrict__ xh,
                     const f16* __restrict__ Wqh, const f16* __restrict__ Wkh,
                     const f16* __restrict__ Wvh,
                     const float* __restrict__ bq, const float* __restrict__ bv,
                     f16* __restrict__ qh, f16* __restrict__ kh, f16* __restrict__ vh,
                     const float* __restrict__ cosp, const float* __restrict__ sinp)
{
    const int mode = blockIdx.z;
    const f16* W = (mode == 0) ? Wqh : (mode == 1 ? Wkh : Wvh);
    const float* bias = (mode == 0) ? bq : (mode == 2 ? bv : nullptr);
    f16* dst = (mode == 0) ? qh : (mode == 1 ? kh : vh);

    __shared__ f16 As[128][40];
    __shared__ f16 Ws[64][40];
    const int tid = threadIdx.x;
    const int w = tid >> 6, l = tid & 63;
    const int lr = l & 15, lq = l >> 4;
    const int m0 = blockIdx.y * 128, n0 = blockIdx.x * 64;

    f32x4 acc[2][4] = {};

    for (int k0 = 0; k0 < Dc; k0 += 32) {
        __syncthreads();
        {
            // A tile: 128 rows x 32 cols = 4096 f16; 16 f16/thread
            int r = tid >> 1, c = (tid & 1) * 16;
            *(f16x8*)&As[r][c]     = *(const f16x8*)&xh[(size_t)(m0 + r) * Dc + k0 + c];
            *(f16x8*)&As[r][c + 8] = *(const f16x8*)&xh[(size_t)(m0 + r) * Dc + k0 + c + 8];
            // W tile: 64 rows x 32 cols = 2048 f16; 8 f16/thread
            int rw = tid >> 2, cw = (tid & 3) * 8;
            *(f16x8*)&Ws[rw][cw] = *(const f16x8*)&W[(size_t)(n0 + rw) * Dc + k0 + cw];
        }
        __syncthreads();
        f16x8 af[2], bf[4];
        #pragma unroll
        for (int mi = 0; mi < 2; mi++) af[mi] = *(const f16x8*)&As[32 * w + 16 * mi + lr][lq * 8];
        #pragma unroll
        for (int ni = 0; ni < 4; ni++) bf[ni] = *(const f16x8*)&Ws[16 * ni + lr][lq * 8];
        #pragma unroll
        for (int mi = 0; mi < 2; mi++)
            #pragma unroll
            for (int ni = 0; ni < 4; ni++)
                acc[mi][ni] = __builtin_amdgcn_mfma_f32_16x16x32_f16(af[mi], bf[ni], acc[mi][ni], 0, 0, 0);
    }

    #pragma unroll
    for (int mi = 0; mi < 2; mi++) {
        #pragma unroll
        for (int ni = 0; ni < 4; ni++) {
            #pragma unroll
            for (int i = 0; i < 4; i++) {
                int gm = m0 + 32 * w + 16 * mi + lq * 4 + i;
                int gn = n0 + 16 * ni + lr;
                float v = acc[mi][ni][i];
                if (bias) v += bias[gn];
                int b = gm >> 11, t = gm & 2047;
                int h = gn >> 6, d = gn & 63;
                if (mode != 2) {
                    float pv = __shfl_xor(v, 1, 64);   // partner col gn^1
                    int p = d >> 1;
                    float c = cosp[t * 32 + p], s = sinp[t * 32 + p];
                    v = (d & 1) ? (pv * s + v * c) : (v * c - pv * s);
                    v *= SCALE;
                }
                dst[((size_t)(b * Hc + h) * Tc + t) * HDc + d] = (f16)v;
            }
        }
    }
}

// ---------------------------------------------------------------------------
// out projection: out(BT x Dc) = wvh * Wo^T + bo, fp32 store (B,T,D)
// ---------------------------------------------------------------------------
__global__ __launch_bounds__(256)
void out_proj_kernel(const f16* __restrict__ A, const f16* __restrict__ W,
                     const float* __restrict__ bias, float* __restrict__ out)
{
    __shared__ f16 As[128][40];
    __shared__ f16 Ws[64][40];
    const int tid = threadIdx.x;
    const int w = tid >> 6, l = tid & 63;
    const int lr = l & 15, lq = l >> 4;
    const int m0 = blockIdx.y * 128, n0 = blockIdx.x * 64;

    f32x4 acc[2][4] = {};

    for (int k0 = 0; k0 < Dc; k0 += 32) {
        __syncthreads();
        {
            int r = tid >> 1, c = (tid & 1) * 16;
            *(f16x8*)&As[r][c]     = *(const f16x8*)&A[(size_t)(m0 + r) * Dc + k0 + c];
            *(f16x8*)&As[r][c + 8] = *(const f16x8*)&A[(size_t)(m0 + r) * Dc + k0 + c + 8];
            int rw = tid >> 2, cw = (tid & 3) * 8;
            *(f16x8*)&Ws[rw][cw] = *(const f16x8*)&W[(size_t)(n0 + rw) * Dc + k0 + cw];
        }
        __syncthreads();
        f16x8 af[2], bf[4];
        #pragma unroll
        for (int mi = 0; mi < 2; mi++) af[mi] = *(const f16x8*)&As[32 * w + 16 * mi + lr][lq * 8];
        #pragma unroll
        for (int ni = 0; ni < 4; ni++) bf[ni] = *(const f16x8*)&Ws[16 * ni + lr][lq * 8];
        #pragma unroll
        for (int mi = 0; mi < 2; mi++)
            #pragma unroll
            for (int ni = 0; ni < 4; ni++)
                acc[mi][ni] = __builtin_amdgcn_mfma_f32_16x16x32_f16(af[mi], bf[ni], acc[mi][ni], 0, 0, 0);
    }

    #pragma unroll
    for (int mi = 0; mi < 2; mi++)
        #pragma unroll
        for (int ni = 0; ni < 4; ni++)
            #pragma unroll
            for (int i = 0; i < 4; i++) {
                int gm = m0 + 32 * w + 16 * mi + lq * 4 + i;
                int gn = n0 + 16 * ni + lr;
                out[(size_t)gm * Dc + gn] = acc[mi][ni][i] + bias[gn];
            }
}

// ---------------------------------------------------------------------------
// qk = q k^T + mask  -> fp32 (output 1).  Per (b,h): tile 128(t) x 64(s).
// Fully-masked tiles: store-only -1e9 fast path.
// ---------------------------------------------------------------------------
__global__ __launch_bounds__(256)
void qk_kernel(const f16* __restrict__ qh, const f16* __restrict__ kh,
               float* __restrict__ qk)
{
    const int z = blockIdx.z;
    const int t0 = blockIdx.y * 128, s0 = blockIdx.x * 64;
    float* C = qk + (size_t)z * Tc * Tc;
    const int tid = threadIdx.x;

    if (s0 > t0 + 127) {           // whole tile masked: |qk value| << 2e7 threshold
        int r = tid >> 1, cb = (tid & 1) * 32;
        float4 mv; mv.x = mv.y = mv.z = mv.w = -1e9f;
        float4* row = (float4*)(C + (size_t)(t0 + r) * Tc + s0 + cb);
        #pragma unroll
        for (int j = 0; j < 8; j++) row[j] = mv;
        return;
    }

    __shared__ f16 Qs[128][72];
    __shared__ f16 Ks[64][72];
    const int w = tid >> 6, l = tid & 63;
    const int lr = l & 15, lq = l >> 4;
    const f16* Qg = qh + (size_t)z * Tc * HDc;
    const f16* Kg = kh + (size_t)z * Tc * HDc;
    {
        // Qs: 128 rows x 64 cols = 8192 f16; 32 f16/thread
        int r = tid >> 1, c = (tid & 1) * 32;
        #pragma unroll
        for (int j = 0; j < 4; j++)
            *(f16x8*)&Qs[r][c + 8 * j] = *(const f16x8*)&Qg[(size_t)(t0 + r) * HDc + c + 8 * j];
        // Ks: 64 rows x 64 cols = 4096 f16; 16 f16/thread
        int rk = tid >> 2, ck = (tid & 3) * 16;
        *(f16x8*)&Ks[rk][ck]     = *(const f16x8*)&Kg[(size_t)(s0 + rk) * HDc + ck];
        *(f16x8*)&Ks[rk][ck + 8] = *(const f16x8*)&Kg[(size_t)(s0 + rk) * HDc + ck + 8];
    }
    __syncthreads();

    f32x4 acc[2][4] = {};
    #pragma unroll
    for (int ks = 0; ks < 2; ks++) {
        f16x8 af[2], bf[4];
        #pragma unroll
        for (int mi = 0; mi < 2; mi++) af[mi] = *(const f16x8*)&Qs[32 * w + 16 * mi + lr][lq * 8 + 32 * ks];
        #pragma unroll
        for (int ni = 0; ni < 4; ni++) bf[ni] = *(const f16x8*)&Ks[16 * ni + lr][lq * 8 + 32 * ks];
        #pragma unroll
        for (int mi = 0; mi < 2; mi++)
            #pragma unroll
            for (int ni = 0; ni < 4; ni++)
                acc[mi][ni] = __builtin_amdgcn_mfma_f32_16x16x32_f16(af[mi], bf[ni], acc[mi][ni], 0, 0, 0);
    }

    #pragma unroll
    for (int mi = 0; mi < 2; mi++)
        #pragma unroll
        for (int ni = 0; ni < 4; ni++)
            #pragma unroll
            for (int i = 0; i < 4; i++) {
                int t = t0 + 32 * w + 16 * mi + lq * 4 + i;
                int s = s0 + 16 * ni + lr;
                float v = acc[mi][ni][i];
                if (s > t) v -= 1e9f;
                C[(size_t)t * Tc + s] = v;
            }
}

// ---------------------------------------------------------------------------
// flash attention: per (b,h, 64-row q-tile), online softmax over s-tiles,
// wv (f16, (B,T,D)) out. Never touches the 512MB qk buffer.
// ---------------------------------------------------------------------------
__global__ __launch_bounds__(256)
void flash_kernel(const f16* __restrict__ qh, const f16* __restrict__ kh,
                  const f16* __restrict__ vh, f16* __restrict__ wvh)
{
    const int z = blockIdx.y;
    const int t0 = (gridDim.x - 1 - blockIdx.x) * 64;   // longest blocks first
    const int tid = threadIdx.x;
    const int w = tid >> 6, l = tid & 63;
    const int lr = l & 15, lq = l >> 4;

    __shared__ f16 Qs[64][72];
    __shared__ f16 Ks[64][72];
    __shared__ f16 VsT[64][72];   // [d][s]
    __shared__ f16 Ps[64][72];    // [m][s]

    const f16* Qg = qh + (size_t)z * Tc * HDc;
    const f16* Kg = kh + (size_t)z * Tc * HDc;
    const f16* Vg = vh + (size_t)z * Tc * HDc;

    {
        int r = tid >> 2, c = (tid & 3) * 16;
        *(f16x8*)&Qs[r][c]     = *(const f16x8*)&Qg[(size_t)(t0 + r) * HDc + c];
        *(f16x8*)&Qs[r][c + 8] = *(const f16x8*)&Qg[(size_t)(t0 + r) * HDc + c + 8];
    }

    f32x4 O[4] = {};
    float mrow[4], lrow[4];
    #pragma unroll
    for (int i = 0; i < 4; i++) { mrow[i] = -1e30f; lrow[i] = 0.f; }

    for (int s0 = 0; s0 <= t0; s0 += 64) {
        __syncthreads();   // prior-iteration LDS reads done (also Qs visibility, iter 0)
        {
            int r = tid >> 2, c = (tid & 3) * 16;
            *(f16x8*)&Ks[r][c]     = *(const f16x8*)&Kg[(size_t)(s0 + r) * HDc + c];
            *(f16x8*)&Ks[r][c + 8] = *(const f16x8*)&Kg[(size_t)(s0 + r) * HDc + c + 8];
        }
        {
            int s = tid & 63, d0 = (tid >> 6) * 16;
            const f16* vp = &Vg[(size_t)(s0 + s) * HDc + d0];
            f16x8 v0 = *(const f16x8*)vp;
            f16x8 v1 = *(const f16x8*)(vp + 8);
            #pragma unroll
            for (int j = 0; j < 8; j++) {
                VsT[d0 + j][s]     = v0[j];
                VsT[d0 + 8 + j][s] = v1[j];
            }
        }
        __syncthreads();

        // S = Q K^T  (wave strip: q-rows 16w..16w+15, all 64 s)
        f32x4 S[4] = {};
        #pragma unroll
        for (int ks = 0; ks < 2; ks++) {
            f16x8 aq = *(const f16x8*)&Qs[16 * w + lr][lq * 8 + 32 * ks];
            #pragma unroll
            for (int ni = 0; ni < 4; ni++) {
                f16x8 bk = *(const f16x8*)&Ks[16 * ni + lr][lq * 8 + 32 * ks];
                S[ni] = __builtin_amdgcn_mfma_f32_16x16x32_f16(aq, bk, S[ni], 0, 0, 0);
            }
        }

        if (s0 == t0) {   // diagonal tile: causal mask
            #pragma unroll
            for (int ni = 0; ni < 4; ni++)
                #pragma unroll
                for (int i = 0; i < 4; i++) {
                    int tg = t0 + 16 * w + lq * 4 + i;
                    int sg = s0 + 16 * ni + lr;
                    if (sg > tg) S[ni][i] = -1e9f;
                }
        }

        // online softmax per row (rows live across 16 lanes of a quad)
        #pragma unroll
        for (int i = 0; i < 4; i++) {
            float v = fmaxf(fmaxf(S[0][i], S[1][i]), fmaxf(S[2][i], S[3][i]));
            v = fmaxf(v, __shfl_xor(v, 1, 64));
            v = fmaxf(v, __shfl_xor(v, 2, 64));
            v = fmaxf(v, __shfl_xor(v, 4, 64));
            v = fmaxf(v, __shfl_xor(v, 8, 64));
            float mnew = fmaxf(mrow[i], v);
            float alpha = __expf(mrow[i] - mnew);
            mrow[i] = mnew;
            float rs = 0.f;
            #pragma unroll
            for (int ni = 0; ni < 4; ni++) {
                float p = __expf(S[ni][i] - mnew);
                S[ni][i] = p;
                rs += p;
            }
            rs += __shfl_xor(rs, 1, 64);
            rs += __shfl_xor(rs, 2, 64);
            rs += __shfl_xor(rs, 4, 64);
            rs += __shfl_xor(rs, 8, 64);
            lrow[i] = lrow[i] * alpha + rs;
            #pragma unroll
            for (int ni = 0; ni < 4; ni++) O[ni][i] *= alpha;
        }

        // P -> LDS (wave-private strip; no cross-wave hazard)
        #pragma unroll
        for (int ni = 0; ni < 4; ni++)
            #pragma unroll
            for (int i = 0; i < 4; i++)
                Ps[16 * w + lq * 4 + i][16 * ni + lr] = (f16)S[ni][i];

        // O += P V
        #pragma unroll
        for (int ks = 0; ks < 2; ks++) {
            f16x8 ap = *(const f16x8*)&Ps[16 * w + lr][lq * 8 + 32 * ks];
            #pragma unroll
            for (int ni = 0; ni < 4; ni++) {
                f16x8 bv = *(const f16x8*)&VsT[16 * ni + lr][lq * 8 + 32 * ks];
                O[ni] = __builtin_amdgcn_mfma_f32_16x16x32_f16(ap, bv, O[ni], 0, 0, 0);
            }
        }
    }

    const int b = z >> 4, h = z & 15;
    #pragma unroll
    for (int ni = 0; ni < 4; ni++)
        #pragma unroll
        for (int i = 0; i < 4; i++) {
            int tg = t0 + 16 * w + lq * 4 + i;
            int d = 16 * ni + lr;
            float o = O[ni][i] / lrow[i];
            wvh[((size_t)(b * Tc + tg)) * Dc + h * HDc + d] = (f16)o;
        }
}

// ---------------------------------------------------------------------------
extern "C" void kernel_launch(void* const* d_in, const int* in_sizes, int n_in,
                              void* d_out, int out_size, void* d_ws, size_t ws_size,
                              hipStream_t stream)
{
    const float* x    = (const float*)d_in[0];
    const float* cosp = (const float*)d_in[2];
    const float* sinp = (const float*)d_in[3];
    const float* Wq   = (const float*)d_in[4];
    const float* bq   = (const float*)d_in[5];
    const float* Wk   = (const float*)d_in[6];
    const float* Wv   = (const float*)d_in[7];
    const float* bv   = (const float*)d_in[8];
    const float* Wo   = (const float*)d_in[9];
    const float* bo   = (const float*)d_in[10];

    float* out = (float*)d_out;
    float* qk  = out + (size_t)BT * Dc;

    f16* ws  = (f16*)d_ws;
    f16* xh  = ws;
    f16* Wqh = xh  + (size_t)BT * Dc;
    f16* Wkh = Wqh + (size_t)Dc * Dc;
    f16* Wvh = Wkh + (size_t)Dc * Dc;
    f16* Woh = Wvh + (size_t)Dc * Dc;
    f16* qh  = Woh + (size_t)Dc * Dc;
    f16* kh  = qh  + (size_t)BT * Dc;
    f16* vh  = kh  + (size_t)BT * Dc;
    f16* wvh = vh  + (size_t)BT * Dc;

    dim3 blk(256);

    cast1_kernel<<<dim3(BT * Dc / 1024), blk, 0, stream>>>(x, xh, BT * Dc / 4);
    cast4_kernel<<<dim3(Dc * Dc / 1024, 4), blk, 0, stream>>>(
        Wq, Wk, Wv, Wo, Wqh, Wkh, Wvh, Woh, Dc * Dc / 4);

    qkv_proj_kernel<<<dim3(Dc / 64, BT / 128, 3), blk, 0, stream>>>(
        xh, Wqh, Wkh, Wvh, bq, bv, qh, kh, vh, cosp, sinp);

    qk_kernel<<<dim3(Tc / 64, Tc / 128, 32), blk, 0, stream>>>(qh, kh, qk);

    flash_kernel<<<dim3(Tc / 64, 32), blk, 0, stream>>>(qh, kh, vh, wvh);

    out_proj_kernel<<<dim3(Dc / 64, BT / 128), blk, 0, stream>>>(wvh, Woh, bo, out);
}

// Round 4
// 779.572 us; speedup vs baseline: 2.1168x; 1.1025x over previous
//
#include <hip/hip_runtime.h>
#include <math.h>

#define Tc 2048
#define Dc 1024
#define Hc 16
#define HDc 64
#define BT 4096                     // B*T
#define SCALE 0.35355339059327379f  // 64^-0.25

typedef _Float16 f16;
typedef __attribute__((ext_vector_type(4))) _Float16 f16x4;
typedef __attribute__((ext_vector_type(8))) _Float16 f16x8;
typedef __attribute__((ext_vector_type(4))) float f32x4;

// ---------------------------------------------------------------------------
// casts
// ---------------------------------------------------------------------------
__global__ __launch_bounds__(256)
void cast1_kernel(const float* __restrict__ in, f16* __restrict__ out, int n4)
{
    int i = blockIdx.x * 256 + threadIdx.x;
    if (i < n4) {
        float4 v = ((const float4*)in)[i];
        f16x4 o = {(f16)v.x, (f16)v.y, (f16)v.z, (f16)v.w};
        ((f16x4*)out)[i] = o;
    }
}

__global__ __launch_bounds__(256)
void cast4_kernel(const float* __restrict__ s0, const float* __restrict__ s1,
                  const float* __restrict__ s2, const float* __restrict__ s3,
                  f16* __restrict__ d0, f16* __restrict__ d1,
                  f16* __restrict__ d2, f16* __restrict__ d3, int n4)
{
    const float* s; f16* d;
    switch (blockIdx.y) {
        case 0:  s = s0; d = d0; break;
        case 1:  s = s1; d = d1; break;
        case 2:  s = s2; d = d2; break;
        default: s = s3; d = d3; break;
    }
    int i = blockIdx.x * 256 + threadIdx.x;
    if (i < n4) {
        float4 v = ((const float4*)s)[i];
        f16x4 o = {(f16)v.x, (f16)v.y, (f16)v.z, (f16)v.w};
        ((f16x4*)d)[i] = o;
    }
}

// ---------------------------------------------------------------------------
// fused QKV projection: C(BT x Dc) = xh * W^T (+bias), epilogue RoPE/scale,
// store f16 (B,H,T,HD).  blockIdx.z: 0=q, 1=k, 2=v
// ---------------------------------------------------------------------------
__global__ __launch_bounds__(256)
void qkv_proj_kernel(const f16* __restrict__ xh,
                     const f16* __restrict__ Wqh, const f16* __restrict__ Wkh,
                     const f16* __restrict__ Wvh,
                     const float* __restrict__ bq, const float* __restrict__ bv,
                     f16* __restrict__ qh, f16* __restrict__ kh, f16* __restrict__ vh,
                     const float* __restrict__ cosp, const float* __restrict__ sinp)
{
    const int mode = blockIdx.z;
    const f16* W = (mode == 0) ? Wqh : (mode == 1 ? Wkh : Wvh);
    const float* bias = (mode == 0) ? bq : (mode == 2 ? bv : nullptr);
    f16* dst = (mode == 0) ? qh : (mode == 1 ? kh : vh);

    __shared__ f16 As[128][40];
    __shared__ f16 Ws[64][40];
    const int tid = threadIdx.x;
    const int w = tid >> 6, l = tid & 63;
    const int lr = l & 15, lq = l >> 4;
    const int m0 = blockIdx.y * 128, n0 = blockIdx.x * 64;

    f32x4 acc[2][4] = {};

    for (int k0 = 0; k0 < Dc; k0 += 32) {
        __syncthreads();
        {
            int r = tid >> 1, c = (tid & 1) * 16;
            *(f16x8*)&As[r][c]     = *(const f16x8*)&xh[(size_t)(m0 + r) * Dc + k0 + c];
            *(f16x8*)&As[r][c + 8] = *(const f16x8*)&xh[(size_t)(m0 + r) * Dc + k0 + c + 8];
            int rw = tid >> 2, cw = (tid & 3) * 8;
            *(f16x8*)&Ws[rw][cw] = *(const f16x8*)&W[(size_t)(n0 + rw) * Dc + k0 + cw];
        }
        __syncthreads();
        f16x8 af[2], bf[4];
        #pragma unroll
        for (int mi = 0; mi < 2; mi++) af[mi] = *(const f16x8*)&As[32 * w + 16 * mi + lr][lq * 8];
        #pragma unroll
        for (int ni = 0; ni < 4; ni++) bf[ni] = *(const f16x8*)&Ws[16 * ni + lr][lq * 8];
        #pragma unroll
        for (int mi = 0; mi < 2; mi++)
            #pragma unroll
            for (int ni = 0; ni < 4; ni++)
                acc[mi][ni] = __builtin_amdgcn_mfma_f32_16x16x32_f16(af[mi], bf[ni], acc[mi][ni], 0, 0, 0);
    }

    #pragma unroll
    for (int mi = 0; mi < 2; mi++) {
        #pragma unroll
        for (int ni = 0; ni < 4; ni++) {
            #pragma unroll
            for (int i = 0; i < 4; i++) {
                int gm = m0 + 32 * w + 16 * mi + lq * 4 + i;
                int gn = n0 + 16 * ni + lr;
                float v = acc[mi][ni][i];
                if (bias) v += bias[gn];
                int b = gm >> 11, t = gm & 2047;
                int h = gn >> 6, d = gn & 63;
                if (mode != 2) {
                    float pv = __shfl_xor(v, 1, 64);   // partner col gn^1
                    int p = d >> 1;
                    float c = cosp[t * 32 + p], s = sinp[t * 32 + p];
                    v = (d & 1) ? (pv * s + v * c) : (v * c - pv * s);
                    v *= SCALE;
                }
                dst[((size_t)(b * Hc + h) * Tc + t) * HDc + d] = (f16)v;
            }
        }
    }
}

// ---------------------------------------------------------------------------
// out projection: out(BT x Dc) = wvh * Wo^T + bo, fp32 store (B,T,D)
// ---------------------------------------------------------------------------
__global__ __launch_bounds__(256)
void out_proj_kernel(const f16* __restrict__ A, const f16* __restrict__ W,
                     const float* __restrict__ bias, float* __restrict__ out)
{
    __shared__ f16 As[128][40];
    __shared__ f16 Ws[64][40];
    const int tid = threadIdx.x;
    const int w = tid >> 6, l = tid & 63;
    const int lr = l & 15, lq = l >> 4;
    const int m0 = blockIdx.y * 128, n0 = blockIdx.x * 64;

    f32x4 acc[2][4] = {};

    for (int k0 = 0; k0 < Dc; k0 += 32) {
        __syncthreads();
        {
            int r = tid >> 1, c = (tid & 1) * 16;
            *(f16x8*)&As[r][c]     = *(const f16x8*)&A[(size_t)(m0 + r) * Dc + k0 + c];
            *(f16x8*)&As[r][c + 8] = *(const f16x8*)&A[(size_t)(m0 + r) * Dc + k0 + c + 8];
            int rw = tid >> 2, cw = (tid & 3) * 8;
            *(f16x8*)&Ws[rw][cw] = *(const f16x8*)&W[(size_t)(n0 + rw) * Dc + k0 + cw];
        }
        __syncthreads();
        f16x8 af[2], bf[4];
        #pragma unroll
        for (int mi = 0; mi < 2; mi++) af[mi] = *(const f16x8*)&As[32 * w + 16 * mi + lr][lq * 8];
        #pragma unroll
        for (int ni = 0; ni < 4; ni++) bf[ni] = *(const f16x8*)&Ws[16 * ni + lr][lq * 8];
        #pragma unroll
        for (int mi = 0; mi < 2; mi++)
            #pragma unroll
            for (int ni = 0; ni < 4; ni++)
                acc[mi][ni] = __builtin_amdgcn_mfma_f32_16x16x32_f16(af[mi], bf[ni], acc[mi][ni], 0, 0, 0);
    }

    #pragma unroll
    for (int mi = 0; mi < 2; mi++)
        #pragma unroll
        for (int ni = 0; ni < 4; ni++)
            #pragma unroll
            for (int i = 0; i < 4; i++) {
                int gm = m0 + 32 * w + 16 * mi + lq * 4 + i;
                int gn = n0 + 16 * ni + lr;
                out[(size_t)gm * Dc + gn] = acc[mi][ni][i] + bias[gn];
            }
}

// ---------------------------------------------------------------------------
// flash attention + S writeback: per (b,h, 64-row q-tile):
//  - online softmax over s-tiles s0 <= t0, storing the post-mask pre-exp S
//    tile to qk (output 1) as it goes
//  - fills the strictly-upper remainder of its 64 rows with -1e9
//  - writes wv (f16, (B,T,D))
// Work self-balances: small-t0 blocks do few flash iters but a big fill.
// ---------------------------------------------------------------------------
__global__ __launch_bounds__(256)
void flash_kernel(const f16* __restrict__ qh, const f16* __restrict__ kh,
                  const f16* __restrict__ vh, f16* __restrict__ wvh,
                  float* __restrict__ qk)
{
    const int z = blockIdx.y;
    const int t0 = (gridDim.x - 1 - blockIdx.x) * 64;   // longest flash loops first
    const int tid = threadIdx.x;
    const int w = tid >> 6, l = tid & 63;
    const int lr = l & 15, lq = l >> 4;

    __shared__ f16 Qs[64][72];
    __shared__ f16 Ks[64][72];
    __shared__ f16 VsT[64][72];   // [d][s]
    __shared__ f16 Ps[64][72];    // [m][s]

    const f16* Qg = qh + (size_t)z * Tc * HDc;
    const f16* Kg = kh + (size_t)z * Tc * HDc;
    const f16* Vg = vh + (size_t)z * Tc * HDc;
    float* C = qk + (size_t)z * Tc * Tc;

    {
        int r = tid >> 2, c = (tid & 3) * 16;
        *(f16x8*)&Qs[r][c]     = *(const f16x8*)&Qg[(size_t)(t0 + r) * HDc + c];
        *(f16x8*)&Qs[r][c + 8] = *(const f16x8*)&Qg[(size_t)(t0 + r) * HDc + c + 8];
    }

    // fill strictly-upper portion of this block's 64 rows: cols [t0+64, Tc)
    {
        int r = t0 + (tid >> 2);             // 4 threads per row
        int n4 = (Tc - t0 - 64) >> 2;        // float4s per row (multiple of 16)
        float4 mv; mv.x = mv.y = mv.z = mv.w = -1e9f;
        float4* rowp = (float4*)(C + (size_t)r * Tc + t0 + 64);
        for (int c = (tid & 3); c < n4; c += 4) rowp[c] = mv;
    }

    f32x4 O[4] = {};
    float mrow[4], lrow[4];
    #pragma unroll
    for (int i = 0; i < 4; i++) { mrow[i] = -1e30f; lrow[i] = 0.f; }

    for (int s0 = 0; s0 <= t0; s0 += 64) {
        __syncthreads();   // prior-iteration LDS reads done (also Qs visibility, iter 0)
        {
            int r = tid >> 2, c = (tid & 3) * 16;
            *(f16x8*)&Ks[r][c]     = *(const f16x8*)&Kg[(size_t)(s0 + r) * HDc + c];
            *(f16x8*)&Ks[r][c + 8] = *(const f16x8*)&Kg[(size_t)(s0 + r) * HDc + c + 8];
        }
        {
            int s = tid & 63, d0 = (tid >> 6) * 16;
            const f16* vp = &Vg[(size_t)(s0 + s) * HDc + d0];
            f16x8 v0 = *(const f16x8*)vp;
            f16x8 v1 = *(const f16x8*)(vp + 8);
            #pragma unroll
            for (int j = 0; j < 8; j++) {
                VsT[d0 + j][s]     = v0[j];
                VsT[d0 + 8 + j][s] = v1[j];
            }
        }
        __syncthreads();

        // S = Q K^T  (wave strip: q-rows 16w..16w+15, all 64 s)
        f32x4 S[4] = {};
        #pragma unroll
        for (int ks = 0; ks < 2; ks++) {
            f16x8 aq = *(const f16x8*)&Qs[16 * w + lr][lq * 8 + 32 * ks];
            #pragma unroll
            for (int ni = 0; ni < 4; ni++) {
                f16x8 bk = *(const f16x8*)&Ks[16 * ni + lr][lq * 8 + 32 * ks];
                S[ni] = __builtin_amdgcn_mfma_f32_16x16x32_f16(aq, bk, S[ni], 0, 0, 0);
            }
        }

        if (s0 == t0) {   // diagonal tile: causal mask
            #pragma unroll
            for (int ni = 0; ni < 4; ni++)
                #pragma unroll
                for (int i = 0; i < 4; i++) {
                    int tg = t0 + 16 * w + lq * 4 + i;
                    int sg = s0 + 16 * ni + lr;
                    if (sg > tg) S[ni][i] = -1e9f;
                }
        }

        // writeback S tile (output 1), post-mask pre-exp
        #pragma unroll
        for (int ni = 0; ni < 4; ni++)
            #pragma unroll
            for (int i = 0; i < 4; i++) {
                int tg = t0 + 16 * w + lq * 4 + i;
                int sg = s0 + 16 * ni + lr;
                C[(size_t)tg * Tc + sg] = S[ni][i];
            }

        // online softmax per row (rows live across 16 lanes of a quad)
        #pragma unroll
        for (int i = 0; i < 4; i++) {
            float v = fmaxf(fmaxf(S[0][i], S[1][i]), fmaxf(S[2][i], S[3][i]));
            v = fmaxf(v, __shfl_xor(v, 1, 64));
            v = fmaxf(v, __shfl_xor(v, 2, 64));
            v = fmaxf(v, __shfl_xor(v, 4, 64));
            v = fmaxf(v, __shfl_xor(v, 8, 64));
            float mnew = fmaxf(mrow[i], v);
            float alpha = __expf(mrow[i] - mnew);
            mrow[i] = mnew;
            float rs = 0.f;
            #pragma unroll
            for (int ni = 0; ni < 4; ni++) {
                float p = __expf(S[ni][i] - mnew);
                S[ni][i] = p;
                rs += p;
            }
            rs += __shfl_xor(rs, 1, 64);
            rs += __shfl_xor(rs, 2, 64);
            rs += __shfl_xor(rs, 4, 64);
            rs += __shfl_xor(rs, 8, 64);
            lrow[i] = lrow[i] * alpha + rs;
            #pragma unroll
            for (int ni = 0; ni < 4; ni++) O[ni][i] *= alpha;
        }

        // P -> LDS (wave-private strip; no cross-wave hazard)
        #pragma unroll
        for (int ni = 0; ni < 4; ni++)
            #pragma unroll
            for (int i = 0; i < 4; i++)
                Ps[16 * w + lq * 4 + i][16 * ni + lr] = (f16)S[ni][i];

        // O += P V
        #pragma unroll
        for (int ks = 0; ks < 2; ks++) {
            f16x8 ap = *(const f16x8*)&Ps[16 * w + lr][lq * 8 + 32 * ks];
            #pragma unroll
            for (int ni = 0; ni < 4; ni++) {
                f16x8 bv = *(const f16x8*)&VsT[16 * ni + lr][lq * 8 + 32 * ks];
                O[ni] = __builtin_amdgcn_mfma_f32_16x16x32_f16(ap, bv, O[ni], 0, 0, 0);
            }
        }
    }

    const int b = z >> 4, h = z & 15;
    #pragma unroll
    for (int ni = 0; ni < 4; ni++)
        #pragma unroll
        for (int i = 0; i < 4; i++) {
            int tg = t0 + 16 * w + lq * 4 + i;
            int d = 16 * ni + lr;
            float o = O[ni][i] / lrow[i];
            wvh[((size_t)(b * Tc + tg)) * Dc + h * HDc + d] = (f16)o;
        }
}

// ---------------------------------------------------------------------------
extern "C" void kernel_launch(void* const* d_in, const int* in_sizes, int n_in,
                              void* d_out, int out_size, void* d_ws, size_t ws_size,
                              hipStream_t stream)
{
    const float* x    = (const float*)d_in[0];
    const float* cosp = (const float*)d_in[2];
    const float* sinp = (const float*)d_in[3];
    const float* Wq   = (const float*)d_in[4];
    const float* bq   = (const float*)d_in[5];
    const float* Wk   = (const float*)d_in[6];
    const float* Wv   = (const float*)d_in[7];
    const float* bv   = (const float*)d_in[8];
    const float* Wo   = (const float*)d_in[9];
    const float* bo   = (const float*)d_in[10];

    float* out = (float*)d_out;
    float* qk  = out + (size_t)BT * Dc;

    f16* ws  = (f16*)d_ws;
    f16* xh  = ws;
    f16* Wqh = xh  + (size_t)BT * Dc;
    f16* Wkh = Wqh + (size_t)Dc * Dc;
    f16* Wvh = Wkh + (size_t)Dc * Dc;
    f16* Woh = Wvh + (size_t)Dc * Dc;
    f16* qh  = Woh + (size_t)Dc * Dc;
    f16* kh  = qh  + (size_t)BT * Dc;
    f16* vh  = kh  + (size_t)BT * Dc;
    f16* wvh = vh  + (size_t)BT * Dc;

    dim3 blk(256);

    cast1_kernel<<<dim3(BT * Dc / 1024), blk, 0, stream>>>(x, xh, BT * Dc / 4);
    cast4_kernel<<<dim3(Dc * Dc / 1024, 4), blk, 0, stream>>>(
        Wq, Wk, Wv, Wo, Wqh, Wkh, Wvh, Woh, Dc * Dc / 4);

    qkv_proj_kernel<<<dim3(Dc / 64, BT / 128, 3), blk, 0, stream>>>(
        xh, Wqh, Wkh, Wvh, bq, bv, qh, kh, vh, cosp, sinp);

    flash_kernel<<<dim3(Tc / 64, 32), blk, 0, stream>>>(qh, kh, vh, wvh, qk);

    out_proj_kernel<<<dim3(Dc / 64, BT / 128), blk, 0, stream>>>(wvh, Woh, bo, out);
}